// Round 1
// baseline (1024.297 us; speedup 1.0000x reference)
//
#include <hip/hip_runtime.h>
#include <math.h>

// FFT-based 2D circular convolution, B=4,C=64,H=251,W=509 -> pad to 256x512.
// z = u + i*k packing trick: one forward 2D FFT gives both spectra.
// DIF forward (natural in -> bit-reversed out), DIT inverse (bit-reversed in
// -> natural out): no bit-reversal permutation ever materialized.

#define H_IN 251
#define W_IN 509
#define HP   256
#define WP   512
#define NIMG 256   // B*C

__device__ __forceinline__ int brev8(int x) { return (int)(__brev((unsigned)x) >> 24); }
__device__ __forceinline__ int brev9(int x) { return (int)(__brev((unsigned)x) >> 23); }

// ---------------- Kernel A: pad+pack + row FFT (512-pt DIF), store transposed.
// grid = nimg*16 blocks of 256 threads; 16 rows (h) per block; LDS = 64 KB.
__global__ __launch_bounds__(256) void kA(const float* __restrict__ u,
                                          const float* __restrict__ kk,
                                          float2* __restrict__ zt,
                                          int img_base) {
    __shared__ float2 tile[16][512];           // exactly 65536 bytes
    const int blk  = blockIdx.x;
    const int imgl = blk >> 4;
    const int h0   = (blk & 15) << 4;
    const int img  = img_base + imgl;
    const int tid  = threadIdx.x;

    // load + zero-pad + pack z = u + i*k (coalesced row reads)
    for (int idx = tid; idx < 16 * 512; idx += 256) {
        const int hh = idx >> 9;
        const int w  = idx & 511;
        const int h  = h0 + hh;
        float ur = 0.f, kr = 0.f;
        if (h < H_IN && w < W_IN) {
            const size_t off = ((size_t)img * H_IN + h) * W_IN + w;
            ur = u[off];
            kr = kk[off];
        }
        tile[hh][w] = make_float2(ur, kr);
    }
    __syncthreads();

    // 9 DIF stages; twiddle shared across the 16 rows handled by this thread
    for (int s = 8; s >= 0; --s) {
        const int m  = 1 << s;
        const int j  = tid & (m - 1);
        const int i1 = ((tid & ~(m - 1)) << 1) | j;
        const int i2 = i1 + m;
        const int e  = j << (8 - s);           // j * (256/m); twiddle = W_512^e
        const float ang = -6.2831853071795864f * (float)e / 512.0f;
        float sn, cs;
        __sincosf(ang, &sn, &cs);
        for (int hh = 0; hh < 16; ++hh) {
            const float2 a = tile[hh][i1];
            const float2 b = tile[hh][i2];
            tile[hh][i1] = make_float2(a.x + b.x, a.y + b.y);
            const float dx = a.x - b.x, dy = a.y - b.y;
            tile[hh][i2] = make_float2(dx * cs - dy * sn, dx * sn + dy * cs);
        }
        __syncthreads();
    }

    // store transposed: zt[(imgl*512 + p)*256 + h]  (p = bit-reversed w-freq pos)
    for (int idx = tid; idx < 16 * 512; idx += 256) {
        const int p  = idx >> 4;
        const int hh = idx & 15;
        zt[((size_t)imgl * 512 + p) * 256 + (size_t)(h0 + hh)] = tile[hh][p];
    }
}

// ---------------- Kernel B: column FFT fwd + pointwise P=U*K + column FFT inv.
// grid = nimg*257; group g handles natural-freq columns w1=g, w2=(512-g)&511.
__global__ __launch_bounds__(256) void kB(float2* __restrict__ zt) {
    __shared__ float2 colA[256];
    __shared__ float2 colB[256];
    const int blk  = blockIdx.x;
    const int imgl = blk / 257;
    const int g    = blk - imgl * 257;
    const int w1   = g;
    const int w2   = (512 - g) & 511;
    const bool self = (w1 == w2);
    const int p1 = brev9(w1);                   // storage position of freq w1
    const int p2 = brev9(w2);
    const int tid = threadIdx.x;

    const size_t baseA = ((size_t)imgl * 512 + p1) * 256;
    const size_t baseB = ((size_t)imgl * 512 + p2) * 256;
    colA[tid] = zt[baseA + tid];                // contiguous 2 KB, coalesced
    colB[tid] = zt[baseB + tid];
    __syncthreads();

    const int col = tid >> 7;                   // wave-uniform: 0->A, 1->B
    const int t   = tid & 127;
    float2* buf = col ? colB : colA;

    // forward DIF 256-pt on both columns (128 butterflies each per stage)
    for (int s = 7; s >= 0; --s) {
        const int m  = 1 << s;
        const int j  = t & (m - 1);
        const int i1 = ((t & ~(m - 1)) << 1) | j;
        const int i2 = i1 + m;
        const int e  = j << (7 - s);            // twiddle = W_256^e
        const float ang = -6.2831853071795864f * (float)e / 256.0f;
        float sn, cs;
        __sincosf(ang, &sn, &cs);
        const float2 a = buf[i1];
        const float2 b = buf[i2];
        buf[i1] = make_float2(a.x + b.x, a.y + b.y);
        const float dx = a.x - b.x, dy = a.y - b.y;
        buf[i2] = make_float2(dx * cs - dy * sn, dx * sn + dy * cs);
        __syncthreads();
    }

    // pointwise: f=(h,w1) pairs with -f=((256-h)&255, w2).  Each thread reads
    // and writes exactly the slots it owns (bijections) -> no barrier needed.
    {
        const int h  = tid;
        const int hm = (256 - h) & 255;
        const int q  = brev8(h);
        const int qm = brev8(hm);
        const float2 Zf = colA[q];
        const float2 Zm = colB[qm];
        // U = 0.5*(Zf + conj(Zm));  K = -0.5i*(Zf - conj(Zm))
        const float2 U = make_float2(0.5f * (Zf.x + Zm.x), 0.5f * (Zf.y - Zm.y));
        const float2 K = make_float2(0.5f * (Zf.y + Zm.y), -0.5f * (Zf.x - Zm.x));
        const float2 P = make_float2(U.x * K.x - U.y * K.y, U.x * K.y + U.y * K.x);
        colA[q]  = P;
        colB[qm] = make_float2(P.x, -P.y);      // P(-f) = conj(P(f))
    }
    __syncthreads();

    // inverse DIT 256-pt (conjugate twiddles), natural-h output
    for (int s = 0; s <= 7; ++s) {
        const int m  = 1 << s;
        const int j  = t & (m - 1);
        const int i1 = ((t & ~(m - 1)) << 1) | j;
        const int i2 = i1 + m;
        const int e  = j << (7 - s);
        const float ang = 6.2831853071795864f * (float)e / 256.0f;
        float sn, cs;
        __sincosf(ang, &sn, &cs);
        const float2 a = buf[i1];
        const float2 b = buf[i2];
        const float2 bw = make_float2(b.x * cs - b.y * sn, b.x * sn + b.y * cs);
        buf[i1] = make_float2(a.x + bw.x, a.y + bw.y);
        buf[i2] = make_float2(a.x - bw.x, a.y - bw.y);
        __syncthreads();
    }

    zt[baseA + tid] = colA[tid];
    if (!self) zt[baseB + tid] = colB[tid];
}

// ---------------- Kernel C: inverse row FFT (512-pt DIT) + scale + crop.
__global__ __launch_bounds__(256) void kC(const float2* __restrict__ zt,
                                          float* __restrict__ y,
                                          int img_base) {
    __shared__ float2 tile[16][512];            // 64 KB
    const int blk  = blockIdx.x;
    const int imgl = blk >> 4;
    const int h0   = (blk & 15) << 4;
    const int img  = img_base + imgl;
    const int tid  = threadIdx.x;

    for (int idx = tid; idx < 16 * 512; idx += 256) {
        const int p  = idx >> 4;
        const int hh = idx & 15;
        tile[hh][p] = zt[((size_t)imgl * 512 + p) * 256 + (size_t)(h0 + hh)];
    }
    __syncthreads();

    for (int s = 0; s <= 8; ++s) {
        const int m  = 1 << s;
        const int j  = tid & (m - 1);
        const int i1 = ((tid & ~(m - 1)) << 1) | j;
        const int i2 = i1 + m;
        const int e  = j << (8 - s);
        const float ang = 6.2831853071795864f * (float)e / 512.0f;
        float sn, cs;
        __sincosf(ang, &sn, &cs);
        for (int hh = 0; hh < 16; ++hh) {
            const float2 a = tile[hh][i1];
            const float2 b = tile[hh][i2];
            const float2 bw = make_float2(b.x * cs - b.y * sn, b.x * sn + b.y * cs);
            tile[hh][i1] = make_float2(a.x + bw.x, a.y + bw.y);
            tile[hh][i2] = make_float2(a.x - bw.x, a.y - bw.y);
        }
        __syncthreads();
    }

    // y = Re(.) * N^{-1.5},  N = 131072  (ortho fwd+inv + conv theorem)
    const float scale = 2.1073424255447017e-08f;   // 2^-25.5
    for (int idx = tid; idx < 16 * 512; idx += 256) {
        const int w  = idx & 511;
        const int hh = idx >> 9;
        const int h  = h0 + hh;
        if (h < H_IN && w < W_IN)
            y[((size_t)img * H_IN + h) * W_IN + w] = tile[hh][w].x * scale;
    }
}

extern "C" void kernel_launch(void* const* d_in, const int* in_sizes, int n_in,
                              void* d_out, int out_size, void* d_ws, size_t ws_size,
                              hipStream_t stream) {
    const float* u = (const float*)d_in[0];
    const float* k = (const float*)d_in[1];
    float* y = (float*)d_out;
    float2* zt = (float2*)d_ws;

    const size_t per_img = (size_t)WP * HP * sizeof(float2);   // 1 MiB
    int chunk = (int)(ws_size / per_img);
    if (chunk > NIMG) chunk = NIMG;
    if (chunk < 1) chunk = 1;

    for (int base = 0; base < NIMG; base += chunk) {
        const int nimg = (NIMG - base < chunk) ? (NIMG - base) : chunk;
        kA<<<dim3(nimg * 16), dim3(256), 0, stream>>>(u, k, zt, base);
        kB<<<dim3(nimg * 257), dim3(256), 0, stream>>>(zt);
        kC<<<dim3(nimg * 16), dim3(256), 0, stream>>>(zt, y, base);
    }
}

// Round 2
// 565.641 us; speedup vs baseline: 1.8109x; 1.8109x over previous
//
#include <hip/hip_runtime.h>
#include <math.h>

// FFT-based 2D circular convolution, B=4,C=64,H=251,W=509 -> pad 256x512.
// z = u + i*k packing; register radix-8 FFTs (8 pts/thread, 2 LDS exchanges);
// all inverse transforms via conj-trick on the forward machinery.
// zt layout: [imgl][w (natural freq)][h] -- columns contiguous (2 KB).

#define H_IN 251
#define W_IN 509
#define NIMG 256
#define LROW 516        // 512 + 4 pad (transpose staging anti-conflict)
#define CSTR 264        // 256 + 8 pad (kB column stride)

__device__ __forceinline__ float2 cadd(float2 a, float2 b){ return make_float2(a.x+b.x, a.y+b.y); }
__device__ __forceinline__ float2 csub(float2 a, float2 b){ return make_float2(a.x-b.x, a.y-b.y); }
__device__ __forceinline__ float2 cmul(float2 a, float2 b){ return make_float2(a.x*b.x-a.y*b.y, a.x*b.y+a.y*b.x); }
__device__ __forceinline__ float2 mnegi(float2 a){ return make_float2(a.y, -a.x); }   // a * (-i)

// 8-pt DFT, natural in -> natural out (DIF + in-register unscramble).
__device__ __forceinline__ void dft8(float2 x[8]) {
    const float s = 0.70710678118654752f;
    float2 y0=cadd(x[0],x[4]), y4=csub(x[0],x[4]);
    float2 y1=cadd(x[1],x[5]), y5=csub(x[1],x[5]);
    float2 y2=cadd(x[2],x[6]), y6=csub(x[2],x[6]);
    float2 y3=cadd(x[3],x[7]), y7=csub(x[3],x[7]);
    y5 = cmul(y5, make_float2(s, -s));
    y6 = mnegi(y6);
    y7 = cmul(y7, make_float2(-s, -s));
    float2 z0=cadd(y0,y2), z2=csub(y0,y2);
    float2 z1=cadd(y1,y3), z3=mnegi(csub(y1,y3));
    float2 z4=cadd(y4,y6), z6=csub(y4,y6);
    float2 z5=cadd(y5,y7), z7=mnegi(csub(y5,y7));
    float2 p0=cadd(z0,z1), p1=csub(z0,z1);
    float2 p2=cadd(z2,z3), p3=csub(z2,z3);
    float2 p4=cadd(z4,z5), p5=csub(z4,z5);
    float2 p6=cadd(z6,z7), p7=csub(z6,z7);
    x[0]=p0; x[1]=p4; x[2]=p2; x[3]=p6; x[4]=p1; x[5]=p5; x[6]=p3; x[7]=p7;
}

// 4-pt DFT, natural in -> natural out.
__device__ __forceinline__ void dft4(float2 x[4]) {
    float2 a=cadd(x[0],x[2]), c=csub(x[0],x[2]);
    float2 b=cadd(x[1],x[3]), d=mnegi(csub(x[1],x[3]));
    float2 p0=cadd(a,b), p1=csub(a,b);
    float2 p2=cadd(c,d), p3=csub(c,d);
    x[0]=p0; x[1]=p2; x[2]=p1; x[3]=p3;
}

// v[q] *= e^{i*ang1*q}, q=1..7
__device__ __forceinline__ void tw8(float2 v[8], float ang1) {
    #pragma unroll
    for (int q = 1; q < 8; ++q) {
        float sn, cs; __sincosf(ang1 * (float)q, &sn, &cs);
        v[q] = cmul(v[q], make_float2(cs, sn));
    }
}

// ---------------- kA: pad+pack + 512-pt row FFT, transposed store (natural freq).
__global__ __launch_bounds__(512, 4) void kA(const float* __restrict__ u,
                                             const float* __restrict__ kk,
                                             float2* __restrict__ zt,
                                             int img_base) {
    __shared__ float2 lds[8][LROW];
    const int imgl = blockIdx.x >> 5;
    const int h0   = (blockIdx.x & 31) << 3;
    const int rr   = threadIdx.x >> 6;
    const int t    = threadIdx.x & 63;
    const int h    = h0 + rr;
    const int img  = img_base + imgl;

    float2 X[8];
    {
        const size_t rowoff = ((size_t)img * H_IN + h) * W_IN;
        #pragma unroll
        for (int r = 0; r < 8; ++r) {
            const int w = t + (r << 6);
            float2 v = make_float2(0.f, 0.f);
            if (h < H_IN && w < W_IN) v = make_float2(u[rowoff + w], kk[rowoff + w]);
            X[r] = v;
        }
    }
    // phase 1: DFT8 over stride-64, twiddle W_512^{t q}
    dft8(X);
    tw8(X, -6.2831853071795864f * (float)t / 512.0f);
    #pragma unroll
    for (int q = 0; q < 8; ++q) lds[rr][(q << 6) + (t ^ (q << 3))] = X[q];
    __syncthreads();

    // phase 2: 8 sub-FFTs of 64; thread -> (q, j1)
    const int q  = t >> 3;
    const int j1 = t & 7;
    float2 Y[8];
    #pragma unroll
    for (int j2 = 0; j2 < 8; ++j2)
        Y[j2] = lds[rr][(q << 6) + ((j1 + (j2 << 3)) ^ (q << 3))];
    dft8(Y);
    tw8(Y, -6.2831853071795864f * (float)j1 / 64.0f);
    __syncthreads();
    #pragma unroll
    for (int q2 = 0; q2 < 8; ++q2) lds[rr][(j1 << 6) + (q2 << 3) + q] = Y[q2];
    __syncthreads();

    // phase 3: DFT8 over j1; freq = 64*q3 + 8*q2 + q
    const int q2 = t & 7;
    float2 Z[8];
    #pragma unroll
    for (int j = 0; j < 8; ++j) Z[j] = lds[rr][(j << 6) + (q2 << 3) + q];
    dft8(Z);
    __syncthreads();
    #pragma unroll
    for (int q3 = 0; q3 < 8; ++q3) lds[rr][(q3 << 6) + (q2 << 3) + q] = Z[q3];
    __syncthreads();

    // transposed store: zt[(imgl*512 + w)*256 + h], 64B h-segments
    for (int idx = threadIdx.x; idx < 8 * 512; idx += 512) {
        const int w  = idx >> 3;
        const int hh = idx & 7;
        zt[((size_t)imgl * 512 + w) * 256 + (size_t)(h0 + hh)] = lds[hh][w];
    }
}

// ---------------- kB: 256-pt column FFT fwd + pointwise + inv (4 conj pairs/block).
__global__ __launch_bounds__(256, 4) void kB(float2* __restrict__ zt) {
    __shared__ float2 spec[8][CSTR];
    const int imgl = blockIdx.x / 65;
    const int bq   = blockIdx.x - imgl * 65;
    const int c    = threadIdx.x >> 5;
    const int t    = threadIdx.x & 31;
    const int pi   = c >> 1, side = c & 1;
    const int g    = (bq << 2) + pi;
    const bool valid = (g <= 256);
    const bool selfp = (g == 0) || (g == 256);
    const int w    = side ? ((512 - g) & 511) : g;
    const size_t colbase = ((size_t)imgl * 512 + w) * 256;

    float2 X[8];
    #pragma unroll
    for (int r = 0; r < 8; ++r) X[r] = zt[colbase + t + (r << 5)];

    const int q  = t >> 2;
    const int j1 = t & 3;
    const int rrq = t & 3;           // q2 low bits for phase 3

    // ======== forward 256-pt ========
    dft8(X);
    tw8(X, -6.2831853071795864f * (float)t / 256.0f);
    #pragma unroll
    for (int qq = 0; qq < 8; ++qq) spec[c][(qq << 5) + (t ^ ((qq & 3) << 3))] = X[qq];
    __syncthreads();

    float2 Y[8];
    #pragma unroll
    for (int j2 = 0; j2 < 8; ++j2)
        Y[j2] = spec[c][(q << 5) + ((j1 + (j2 << 2)) ^ ((q & 3) << 3))];
    dft8(Y);
    tw8(Y, -6.2831853071795864f * (float)j1 / 32.0f);
    __syncthreads();
    #pragma unroll
    for (int q2 = 0; q2 < 8; ++q2) spec[c][(j1 << 6) + (q2 << 3) + q] = Y[q2];
    __syncthreads();

    float2 Za[4], Zb[4];
    #pragma unroll
    for (int j = 0; j < 4; ++j) Za[j] = spec[c][(j << 6) + (rrq << 3) + q];
    #pragma unroll
    for (int j = 0; j < 4; ++j) Zb[j] = spec[c][(j << 6) + ((rrq + 4) << 3) + q];
    dft4(Za); dft4(Zb);
    __syncthreads();
    #pragma unroll
    for (int k = 0; k < 4; ++k) spec[c][(k << 6) + (rrq << 3) + q] = Za[k];
    #pragma unroll
    for (int k = 0; k < 4; ++k) spec[c][(k << 6) + ((rrq + 4) << 3) + q] = Zb[k];
    __syncthreads();

    // ======== pointwise P = U*K (pair columns cA=2*pair, cB=cA+1) ========
    {
        const int ti = threadIdx.x & 63;
        const int cA = (threadIdx.x >> 6) << 1;
        #pragma unroll
        for (int hi = 0; hi < 4; ++hi) {
            const int h  = ti + (hi << 6);
            const int hm = (256 - h) & 255;
            const float2 Zf = spec[cA][h];
            const float2 Zm = spec[cA + 1][hm];
            const float2 U = make_float2(0.5f * (Zf.x + Zm.x),  0.5f * (Zf.y - Zm.y));
            const float2 K = make_float2(0.5f * (Zf.y + Zm.y), -0.5f * (Zf.x - Zm.x));
            const float2 P = cmul(U, K);
            spec[cA][h]      = P;
            spec[cA + 1][hm] = make_float2(P.x, -P.y);
        }
    }
    __syncthreads();

    // ======== inverse 256-pt via conj-trick ========
    #pragma unroll
    for (int r = 0; r < 8; ++r) {
        float2 v = spec[c][t + (r << 5)];
        X[r] = make_float2(v.x, -v.y);
    }
    __syncthreads();
    dft8(X);
    tw8(X, -6.2831853071795864f * (float)t / 256.0f);
    #pragma unroll
    for (int qq = 0; qq < 8; ++qq) spec[c][(qq << 5) + (t ^ ((qq & 3) << 3))] = X[qq];
    __syncthreads();
    #pragma unroll
    for (int j2 = 0; j2 < 8; ++j2)
        Y[j2] = spec[c][(q << 5) + ((j1 + (j2 << 2)) ^ ((q & 3) << 3))];
    dft8(Y);
    tw8(Y, -6.2831853071795864f * (float)j1 / 32.0f);
    __syncthreads();
    #pragma unroll
    for (int q2 = 0; q2 < 8; ++q2) spec[c][(j1 << 6) + (q2 << 3) + q] = Y[q2];
    __syncthreads();
    #pragma unroll
    for (int j = 0; j < 4; ++j) Za[j] = spec[c][(j << 6) + (rrq << 3) + q];
    #pragma unroll
    for (int j = 0; j < 4; ++j) Zb[j] = spec[c][(j << 6) + ((rrq + 4) << 3) + q];
    dft4(Za); dft4(Zb);
    __syncthreads();
    #pragma unroll
    for (int k = 0; k < 4; ++k)
        spec[c][(k << 6) + (rrq << 3) + q] = make_float2(Za[k].x, -Za[k].y);
    #pragma unroll
    for (int k = 0; k < 4; ++k)
        spec[c][(k << 6) + ((rrq + 4) << 3) + q] = make_float2(Zb[k].x, -Zb[k].y);
    __syncthreads();

    // write back (skip duplicate of self-paired column and masked g>256)
    if (valid && !(side && selfp)) {
        #pragma unroll
        for (int r = 0; r < 8; ++r) {
            const int h = t + (r << 5);
            zt[colbase + h] = spec[c][h];
        }
    }
}

// ---------------- kC: 512-pt inverse row FFT (conj-trick) + scale + crop.
__global__ __launch_bounds__(512, 4) void kC(const float2* __restrict__ zt,
                                             float* __restrict__ y,
                                             int img_base) {
    __shared__ float2 lds[8][LROW];
    const int imgl = blockIdx.x >> 5;
    const int h0   = (blockIdx.x & 31) << 3;
    const int rr   = threadIdx.x >> 6;
    const int t    = threadIdx.x & 63;
    const int img  = img_base + imgl;

    // load transposed chunk (64B h-segments), natural freq w
    for (int idx = threadIdx.x; idx < 8 * 512; idx += 512) {
        const int w  = idx >> 3;
        const int hh = idx & 7;
        lds[hh][w] = zt[((size_t)imgl * 512 + w) * 256 + (size_t)(h0 + hh)];
    }
    __syncthreads();

    float2 X[8];
    #pragma unroll
    for (int r = 0; r < 8; ++r) {
        float2 v = lds[rr][t + (r << 6)];
        X[r] = make_float2(v.x, -v.y);      // conj for inverse
    }
    __syncthreads();

    dft8(X);
    tw8(X, -6.2831853071795864f * (float)t / 512.0f);
    #pragma unroll
    for (int q = 0; q < 8; ++q) lds[rr][(q << 6) + (t ^ (q << 3))] = X[q];
    __syncthreads();

    const int q  = t >> 3;
    const int j1 = t & 7;
    float2 Y[8];
    #pragma unroll
    for (int j2 = 0; j2 < 8; ++j2)
        Y[j2] = lds[rr][(q << 6) + ((j1 + (j2 << 3)) ^ (q << 3))];
    dft8(Y);
    tw8(Y, -6.2831853071795864f * (float)j1 / 64.0f);
    __syncthreads();
    #pragma unroll
    for (int q2 = 0; q2 < 8; ++q2) lds[rr][(j1 << 6) + (q2 << 3) + q] = Y[q2];
    __syncthreads();

    const int q2 = t & 7;
    float2 Z[8];
    #pragma unroll
    for (int j = 0; j < 8; ++j) Z[j] = lds[rr][(j << 6) + (q2 << 3) + q];
    dft8(Z);
    __syncthreads();
    #pragma unroll
    for (int q3 = 0; q3 < 8; ++q3) lds[rr][(q3 << 6) + (q2 << 3) + q] = Z[q3];
    __syncthreads();

    const float scale = 2.1073424255447017e-08f;   // N^{-1.5}, N=131072
    for (int idx = threadIdx.x; idx < 8 * 512; idx += 512) {
        const int w  = idx & 511;
        const int hh = idx >> 9;
        const int h  = h0 + hh;
        if (h < H_IN && w < W_IN)
            y[((size_t)img * H_IN + h) * W_IN + w] = lds[hh][w].x * scale;
    }
}

extern "C" void kernel_launch(void* const* d_in, const int* in_sizes, int n_in,
                              void* d_out, int out_size, void* d_ws, size_t ws_size,
                              hipStream_t stream) {
    const float* u = (const float*)d_in[0];
    const float* k = (const float*)d_in[1];
    float* y = (float*)d_out;
    float2* zt = (float2*)d_ws;

    const size_t per_img = (size_t)512 * 256 * sizeof(float2);   // 1 MiB
    int chunk = (int)(ws_size / per_img);
    if (chunk > NIMG) chunk = NIMG;
    if (chunk < 1) chunk = 1;

    for (int base = 0; base < NIMG; base += chunk) {
        const int nimg = (NIMG - base < chunk) ? (NIMG - base) : chunk;
        kA<<<dim3(nimg * 32), dim3(512), 0, stream>>>(u, k, zt, base);
        kB<<<dim3(nimg * 65), dim3(256), 0, stream>>>(zt);
        kC<<<dim3(nimg * 32), dim3(512), 0, stream>>>(zt, y, base);
    }
}